// Round 2
// baseline (79.707 us; speedup 1.0000x reference)
//
#include <hip/hip_runtime.h>

#define NORB 13
#define FEAT 107
#define TWO_PI 6.28318530717958647692f

// Per-thread computation of the (p,q) -> feature-index map for the
// upper-tri orbital-pair layout. 15 iterations, run once per thread.
// Basis: l = [0,0,1,1,2] -> dims [1,1,3,3,5], offsets [0,1,2,5,8,13].
__device__ __forceinline__ void map_pq(int p, int q, int& idx, float& scl) {
    const int DIMS[5] = {1, 1, 3, 3, 5};
    const int OFFS[5] = {0, 1, 2, 5, 8};
    idx = -1; scl = 0.0f;
    int o = 0;
    #pragma unroll
    for (int i = 0; i < 5; ++i) {
        #pragma unroll
        for (int j = i; j < 5; ++j) {
            int di = DIMS[i], dj = DIMS[j];
            if (p >= OFFS[i] && p < OFFS[i] + di && q >= OFFS[j] && q < OFFS[j] + dj) {
                idx = o + (p - OFFS[i]) * dj + (q - OFFS[j]);
                scl = (i == j) ? 0.5f : 1.0f;
            }
            o += di * dj;
        }
    }
}

// ---- kernel 1: zero the whole output buffer (float4 grid-stride) ----
__global__ void zero_kernel(float4* __restrict__ out, long n4) {
    long i = (long)blockIdx.x * blockDim.x + threadIdx.x;
    long stride = (long)gridDim.x * blockDim.x;
    float4 z = make_float4(0.f, 0.f, 0.f, 0.f);
    for (; i < n4; i += stride) out[i] = z;
}

// ---- kernel 2: onsite diagonal blocks (plain stores, after zero) ----
// Out[k, a*13+p, a*13+q] (real part) = M[p][q] + M[q][p]; imag stays 0.
template <int CPX>
__global__ void onsite_kernel(const float* __restrict__ onsite, float* __restrict__ out,
                              int K, long nn) {
    int a = blockIdx.x;
    int t = threadIdx.x;
    if (t >= NORB * NORB) return;
    int p = t / NORB, q = t % NORB;
    int i1, i2; float s1, s2;
    map_pq(p, q, i1, s1);
    map_pq(q, p, i2, s2);
    const float* f = onsite + (long)a * FEAT;
    float v = 0.0f;
    if (i1 >= 0) v += s1 * f[i1];
    if (i2 >= 0) v += s2 * f[i2];
    long row = (long)a * NORB + p;
    long col = (long)a * NORB + q;
    for (int k = 0; k < K; ++k) {
        long off = (((long)k * nn + row) * nn + col) * CPX;
        out[off] = v;   // real; imag (if present) already zero
    }
}

// ---- kernel 3: edge scatter with atomics ----
// Out[k, ei*13+p, ej*13+q] += phase_k * h[p][q]
// Out[k, ej*13+q, ei*13+p] += conj(phase_k) * h[p][q]
template <int CPX>
__global__ void edge_kernel(const float* __restrict__ hop, const float* __restrict__ kpts,
                            const float* __restrict__ shift, const int* __restrict__ eidx,
                            float* __restrict__ out, int E, int K, long nn) {
    int e = blockIdx.x;
    int t = threadIdx.x;
    __shared__ float phc[16], phs[16];
    int ei = eidx[e];
    int ej = eidx[E + e];
    if (t < K && t < 16) {
        float rx = shift[(long)e * 3 + 0];
        float ry = shift[(long)e * 3 + 1];
        float rz = shift[(long)e * 3 + 2];
        float th = -TWO_PI * (kpts[t * 3 + 0] * rx + kpts[t * 3 + 1] * ry + kpts[t * 3 + 2] * rz);
        float s, c;
        __sincosf(th, &s, &c);
        phc[t] = c; phs[t] = s;
    }
    __syncthreads();
    if (t >= NORB * NORB) return;
    int p = t / NORB, q = t % NORB;
    int idx; float scl;
    map_pq(p, q, idx, scl);
    if (idx < 0) return;   // structurally zero entry — no atomics
    float v = scl * hop[(long)e * FEAT + idx];
    long r1 = (long)ei * NORB + p, c1 = (long)ej * NORB + q;
    long r2 = (long)ej * NORB + q, c2 = (long)ei * NORB + p;
    for (int k = 0; k < K; ++k) {
        float pr = phc[k], pi = phs[k];
        long o1 = (((long)k * nn + r1) * nn + c1) * CPX;
        long o2 = (((long)k * nn + r2) * nn + c2) * CPX;
        atomicAdd(&out[o1], pr * v);
        atomicAdd(&out[o2], pr * v);
        if (CPX == 2) {
            atomicAdd(&out[o1 + 1], pi * v);
            atomicAdd(&out[o2 + 1], -pi * v);
        }
    }
}

extern "C" void kernel_launch(void* const* d_in, const int* in_sizes, int n_in,
                              void* d_out, int out_size, void* d_ws, size_t ws_size,
                              hipStream_t stream) {
    const float* hop  = (const float*)d_in[0];
    const float* ons  = (const float*)d_in[1];
    const float* kpt  = (const float*)d_in[2];
    const float* shf  = (const float*)d_in[3];
    const int*   eidx = (const int*)d_in[4];

    int E = in_sizes[0] / FEAT;    // 4096
    int N = in_sizes[1] / FEAT;    // 256
    int K = in_sizes[2] / 3;       // 4
    long nn = (long)N * NORB;      // 3328

    float* out = (float*)d_out;

    // Layout detection: out_size is either K*nn*nn*2 float32 elements
    // (complex64 viewed as interleaved floats) or K*nn*nn (real-only view).
    long knn2 = (long)K * nn * nn * 2;
    int cpx = ((long)out_size >= knn2) ? 2 : 1;

    // Zero exactly the buffer the validator reads (out_size floats, /4 exact).
    long n4 = (long)out_size / 4;
    zero_kernel<<<2048, 256, 0, stream>>>((float4*)out, n4);

    if (cpx == 2) {
        onsite_kernel<2><<<N, 192, 0, stream>>>(ons, out, K, nn);
        edge_kernel<2><<<E, 192, 0, stream>>>(hop, kpt, shf, eidx, out, E, K, nn);
    } else {
        onsite_kernel<1><<<N, 192, 0, stream>>>(ons, out, K, nn);
        edge_kernel<1><<<E, 192, 0, stream>>>(hop, kpt, shf, eidx, out, E, K, nn);
    }
}